// Round 19
// baseline (589.448 us; speedup 1.0000x reference)
//
#include <hip/hip_runtime.h>
#include <hip/hip_bf16.h>
#include <math.h>

#define S_LEN 1024
#define B_DIM 4
#define EMB 128
#define HID 768
#define LAYERS 4
#define CW 3
#define NHEAD 12
#define HDIM 64
#define T_LEN (S_LEN - 4*CW)   // 1012
#define LN_EPS 1e-5f
#define MROWS (S_LEN*B_DIM)    // 4096

typedef unsigned short u16;
typedef __attribute__((ext_vector_type(8))) __bf16 bf16x8;
typedef __attribute__((ext_vector_type(4))) float f32x4;

__device__ __forceinline__ u16 f2b(float f){
    unsigned u = __float_as_uint(f);
    u += 0x7fff + ((u >> 16) & 1);          // round-to-nearest-even
    return (u16)(u >> 16);
}
__device__ __forceinline__ float b2f(u16 h){
    return __uint_as_float(((unsigned)h) << 16);
}
__device__ __forceinline__ float gelu_exact(float x){
    return 0.5f * x * (1.0f + erff(x * 0.70710678118654752f));
}
__device__ __forceinline__ float softplus_f(float x){
    return fmaxf(x, 0.0f) + log1pf(expf(-fabsf(x)));
}
template<int N> __device__ __forceinline__ void waitcnt_vm(){
    if constexpr(N==0) asm volatile("s_waitcnt vmcnt(0)" ::: "memory");
    else if constexpr(N==2) asm volatile("s_waitcnt vmcnt(2)" ::: "memory");
    else if constexpr(N==3) asm volatile("s_waitcnt vmcnt(3)" ::: "memory");
    else if constexpr(N==4) asm volatile("s_waitcnt vmcnt(4)" ::: "memory");
    else if constexpr(N==6) asm volatile("s_waitcnt vmcnt(6)" ::: "memory");
    else if constexpr(N==8) asm volatile("s_waitcnt vmcnt(8)" ::: "memory");
    else if constexpr(N==12) asm volatile("s_waitcnt vmcnt(12)" ::: "memory");
}

// ---------------- f32 -> bf16 weight conversion ----------------
__global__ void k_cvt(const float* __restrict__ w, u16* __restrict__ o, int n4){
    int i = blockIdx.x*256 + threadIdx.x;
    if(i >= n4) return;
    float4 v = *(const float4*)(w + (size_t)i*4);
    ushort4 t; t.x=f2b(v.x); t.y=f2b(v.y); t.z=f2b(v.z); t.w=f2b(v.w);
    *(ushort4*)(o + (size_t)i*4) = t;
}

// ---------------- positional encoding table (S, HID) ----------------
__global__ void k_pe(float* __restrict__ pe){
    int idx = blockIdx.x*256 + threadIdx.x;
    if(idx >= S_LEN*HID) return;
    int s = idx / HID, c = idx % HID;
    int i2 = (c >> 1) * 2;
    float freq = expf(-(float)i2 * (logf(10000.0f) / (float)HID));
    float ang = (float)s * freq;
    pe[idx] = (c & 1) ? cosf(ang) : sinf(ang);
}

// ---------------- z = LN(emb_table[seq^T]) : f32 + bf16 copies ----------------
__global__ void k_embed_ln(const int* __restrict__ seq,
                           const float* __restrict__ emb,
                           const float* __restrict__ g,
                           const float* __restrict__ bta,
                           float* __restrict__ z, u16* __restrict__ zb){
    int row = blockIdx.x;
    int s = row >> 2, b = row & 3;
    int tok = seq[b*S_LEN + s];
    const float* e = emb + (size_t)tok * EMB;
    int lane = threadIdx.x;
    float v0 = e[lane], v1 = e[lane+64];
    float sum = v0+v1, sq = v0*v0+v1*v1;
    #pragma unroll
    for(int off=32; off; off>>=1){ sum += __shfl_xor(sum,off); sq += __shfl_xor(sq,off); }
    float m = sum * (1.0f/128.0f);
    float var = sq*(1.0f/128.0f) - m*m;
    float r = rsqrtf(var + LN_EPS);
    size_t base = (size_t)row*EMB;
    float o0 = (v0-m)*r*g[lane]    + bta[lane];
    float o1 = (v1-m)*r*g[lane+64] + bta[lane+64];
    z[base+lane] = o0; z[base+lane+64] = o1;
    zb[base+lane] = f2b(o0); zb[base+lane+64] = f2b(o1);
}

// ---------------- MFMA GEMM: C[M,N] = A_bf16[M,K] * B_bf16[N,K]^T (+bias) ---
// BMxBN tile, BK in {32,64}, THR threads, WC wave-columns, NBUF LDS buffers,
// SK-way split-K.
// NBUF=3: prefetch-1, single barrier/K-step. NBUF=2: 2 barriers (WAR).
// BK=32 chunk swizzle u^((row>>1)&3); BK=64: u^(row&7). Swizzle applied on
// pre-swizzled global source AND ds_read side (rule #21).
// Counted s_waitcnt vmcnt keeps prefetched tile in flight across barriers.
// s_setprio(1) around MFMA cluster (T5).
// EPI: 0 +bias, 1 gelu(+bias), 2 gelu(+bias)+pe,
//      3 slice-partial bf16 write (no bias): Cb[slice*M*N + row*N + col].
template<int BM, int BN, int BK, int THR, int WC, int NBUF, int SK,
         int EPI, int WF, int WB>
__global__ __launch_bounds__(THR) void k_mm(
    const u16*  __restrict__ A,
    const u16*  __restrict__ Bw,
    const float* __restrict__ bias,
    float* __restrict__ Cf, u16* __restrict__ Cb,
    int M, int N, int K, const float* __restrict__ pe)
{
    constexpr int NW = THR/64;
    constexpr int WROW = NW/WC;
    constexpr int WM = BM/WROW, WN = BN/WC, MR = WM/16, NR = WN/16;
    constexpr int ROWB = BK*2;                 // bytes per LDS row
    constexpr int CM = ROWB/16 - 1;            // chunk mask (3 or 7)
    constexpr int RA = (BM*ROWB)/(THR*16);     // stage rounds for A (>=1)
    constexpr int RB = (BN*ROWB)/(THR*16);     // stage rounds for B (>=1)
    constexpr int IC = RA + RB;                // gload_lds issues/thread/tile
    static_assert(RA >= 1 && RB >= 1, "tile too small for THR");
    __shared__ u16 Al[NBUF][BM*BK];
    __shared__ u16 Bl[NBUF][BN*BK];
    int tid = threadIdx.x;
    int wave = tid >> 6, lane = tid & 63;

    // 1D grid: slice-slowest / rows-slow / cols-fast + bijective XCD swizzle
    int nbx = N / BN, nby = M / BM, nwg = nbx * nby * SK;
    int bid = blockIdx.x;
    int q = nwg >> 3, rm = nwg & 7, xcd = bid & 7, off = bid >> 3;
    int sbid = (xcd < rm ? xcd*(q+1) : rm*(q+1) + (xcd-rm)*q) + off;
    int slice = sbid / (nbx*nby);
    int rb2 = sbid % (nbx*nby);
    int row0 = (rb2 / nbx) * BM, col0 = (rb2 % nbx) * BN;
    int kb = slice * (K / SK);

    int wr = wave / WC, wc = wave % WC;
    int lr = lane & 15, lk = lane >> 4;

    f32x4 acc[MR][NR];
    #pragma unroll
    for(int m=0;m<MR;m++)
        #pragma unroll
        for(int n=0;n<NR;n++) acc[m][n] = (f32x4){0.f,0.f,0.f,0.f};

    const char* Abase = (const char*)A;
    const char* Bbase = (const char*)Bw;

    auto swz = [](int u, int rr)->int{
        if constexpr(BK==32) return u ^ ((rr>>1)&3);
        else                 return u ^ (rr & CM);
    };
    auto stage = [&](int buf, int k0){
        #pragma unroll
        for(int i=0;i<RA;i++){
            int p = i*(THR*16) + tid*16;               // byte offset in tile
            int rr = p / ROWB, u = (p >> 4) & CM;
            int us = swz(u, rr);
            const char* g = Abase + ((size_t)(row0+rr)*K + k0)*2 + us*16;
            void* l = (char*)&Al[buf][0] + i*(THR*16) + wave*1024;  // wave-uniform
            __builtin_amdgcn_global_load_lds(
                (const __attribute__((address_space(1))) void*)g,
                (__attribute__((address_space(3))) void*)l, 16, 0, 0);
        }
        #pragma unroll
        for(int i=0;i<RB;i++){
            int p = i*(THR*16) + tid*16;
            int rr = p / ROWB, u = (p >> 4) & CM;
            int us = swz(u, rr);
            const char* g = Bbase + ((size_t)(col0+rr)*K + k0)*2 + us*16;
            void* l = (char*)&Bl[buf][0] + i*(THR*16) + wave*1024;
            __builtin_amdgcn_global_load_lds(
                (const __attribute__((address_space(1))) void*)g,
                (__attribute__((address_space(3))) void*)l, 16, 0, 0);
        }
    };

    int nt = (K / SK) / BK;
    stage(0, kb);
    int cur = 0;
    for(int t=0; t<nt; ++t){
        if constexpr(NBUF==3){
            // prefetch-1, single barrier: write (t+1)%3, reads t%3 / (t-1)%3
            int nxt = (cur==2) ? 0 : cur+1;
            if(t+1 < nt){ stage(nxt, kb + (t+1)*BK); waitcnt_vm<IC>(); }
            else        { waitcnt_vm<0>(); }
            __builtin_amdgcn_s_barrier();
            __builtin_amdgcn_sched_barrier(0);
        } else {
            if(t+1 < nt){ stage(cur^1, kb + (t+1)*BK); waitcnt_vm<IC>(); }
            else        { waitcnt_vm<0>(); }
            __builtin_amdgcn_s_barrier();
            __builtin_amdgcn_sched_barrier(0);
        }
        #pragma unroll
        for(int kk=0; kk<BK/32; ++kk){
            bf16x8 af[MR], bfr[NR];
            #pragma unroll
            for(int m=0;m<MR;m++){
                int ar = wr*WM + m*16 + lr;
                int c  = swz(kk*4 + lk, ar);
                af[m] = *(const bf16x8*)((const char*)&Al[cur][0] + ar*ROWB + (c<<4));
            }
            #pragma unroll
            for(int n=0;n<NR;n++){
                int br = wc*WN + n*16 + lr;
                int c  = swz(kk*4 + lk, br);
                bfr[n] = *(const bf16x8*)((const char*)&Bl[cur][0] + br*ROWB + (c<<4));
            }
            __builtin_amdgcn_s_setprio(1);
            #pragma unroll
            for(int m=0;m<MR;m++)
                #pragma unroll
                for(int n=0;n<NR;n++)
                    acc[m][n] = __builtin_amdgcn_mfma_f32_16x16x32_bf16(af[m], bfr[n], acc[m][n], 0, 0, 0);
            __builtin_amdgcn_s_setprio(0);
        }
        if constexpr(NBUF==3){
            cur = (cur==2) ? 0 : cur+1;     // no trailing barrier
        } else {
            __builtin_amdgcn_s_barrier();   // WAR barrier for 2-buffer
            cur ^= 1;
        }
    }
    // epilogue: C/D layout col=lane&15, row=(lane>>4)*4+j
    #pragma unroll
    for(int m=0;m<MR;m++){
        #pragma unroll
        for(int n=0;n<NR;n++){
            #pragma unroll
            for(int j=0;j<4;j++){
                int row = row0 + wr*WM + m*16 + lk*4 + j;
                int col = col0 + wc*WN + n*16 + lr;
                float v = acc[m][n][j];
                if constexpr(EPI==3){
                    Cb[(size_t)slice*M*N + (size_t)row*N + col] = f2b(v);
                } else {
                    v += bias[col];
                    if(EPI==1) v = gelu_exact(v);
                    if(EPI==2) v = gelu_exact(v) + pe[(size_t)(row>>2)*HID + col];
                    if(WF) Cf[(size_t)row*N + col] = v;
                    if(WB) Cb[(size_t)row*N + col] = f2b(v);
                }
            }
        }
    }
}

// ---------------- banded attention, MFMA QK^T ----------------
__global__ __launch_bounds__(256) void k_attn(const u16* __restrict__ qkv,
                                              u16* __restrict__ out){
    __shared__ float P[4][16][36];
    int wv = threadIdx.x >> 6;
    int lane = threadIdx.x & 63;
    int wid = (blockIdx.x << 2) + wv;      // 0..3071
    int h = wid % NHEAD;
    int b = (wid / NHEAD) & 3;
    int s0 = (wid / (NHEAD*B_DIM)) << 4;   // query tile base
    int lr = lane & 15, lk = lane >> 4;
    const int RS = 3*HID;                  // 2304

    bf16x8 qf[2], kf[2][2];
    #pragma unroll
    for(int kk=0;kk<2;kk++)
        qf[kk] = *(const bf16x8*)(qkv + (size_t)((s0+lr)*B_DIM + b)*RS + h*HDIM + kk*32 + lk*8);
    #pragma unroll
    for(int c=0;c<2;c++){
        int t = s0 + c*16 + lr; if(t > S_LEN-1) t = S_LEN-1;
        #pragma unroll
        for(int kk=0;kk<2;kk++)
            kf[c][kk] = *(const bf16x8*)(qkv + (size_t)(t*B_DIM + b)*RS + HID + h*HDIM + kk*32 + lk*8);
    }
    f32x4 acc0 = {0.f,0.f,0.f,0.f}, acc1 = {0.f,0.f,0.f,0.f};
    #pragma unroll
    for(int kk=0;kk<2;kk++){
        acc0 = __builtin_amdgcn_mfma_f32_16x16x32_bf16(qf[kk], kf[0][kk], acc0, 0,0,0);
        acc1 = __builtin_amdgcn_mfma_f32_16x16x32_bf16(qf[kk], kf[1][kk], acc1, 0,0,0);
    }
    float e0[4], e1[4], mx[4], sm[4];
    #pragma unroll
    for(int j=0;j<4;j++){
        int r = 4*lk + j;
        int g0 = lr - r, g1 = 16 + lr - r;
        bool a0 = (g0>=0) & (g0<=12) & (g0!=6);
        bool a1 = (g1>=0) & (g1<=12) & (g1!=6) & (s0+16+lr < S_LEN);
        e0[j] = a0 ? acc0[j]*0.125f : -INFINITY;
        e1[j] = a1 ? acc1[j]*0.125f : -INFINITY;
        mx[j] = fmaxf(e0[j], e1[j]);
    }
    #pragma unroll
    for(int off=1; off<16; off<<=1){
        #pragma unroll
        for(int j=0;j<4;j++) mx[j] = fmaxf(mx[j], __shfl_xor(mx[j], off));
    }
    #pragma unroll
    for(int j=0;j<4;j++){
        e0[j] = expf(e0[j]-mx[j]);
        e1[j] = expf(e1[j]-mx[j]);
        sm[j] = e0[j]+e1[j];
    }
    #pragma unroll
    for(int off=1; off<16; off<<=1){
        #pragma unroll
        for(int j=0;j<4;j++) sm[j] += __shfl_xor(sm[j], off);
    }
    #pragma unroll
    for(int j=0;j<4;j++){
        float inv = 1.0f/sm[j];
        int r = 4*lk + j;
        P[wv][r][lr]      = e0[j]*inv;
        P[wv][r][16+lr]   = e1[j]*inv;
    }
    float o[16];
    #pragma unroll
    for(int r=0;r<16;r++) o[r] = 0.f;
    #pragma unroll
    for(int g4=0; g4<32; g4+=4){
        float vr[4];
        #pragma unroll
        for(int qq=0;qq<4;qq++){
            int t = s0 + g4 + qq; if(t > S_LEN-1) t = S_LEN-1;
            vr[qq] = b2f(qkv[(size_t)(t*B_DIM + b)*RS + 2*HID + h*HDIM + lane]);
        }
        #pragma unroll
        for(int r=0;r<16;r++){
            f32x4 w = *(const f32x4*)&P[wv][r][g4];
            o[r] = fmaf(w[0], vr[0], fmaf(w[1], vr[1], fmaf(w[2], vr[2], fmaf(w[3], vr[3], o[r]))));
        }
    }
    #pragma unroll
    for(int r=0;r<16;r++)
        out[(size_t)((s0+r)*B_DIM + b)*HID + h*HDIM + lane] = f2b(o[r]);
}

// ------- xb = LN(xb + y0 + y1 + ybias) over 768 (split-K slice sum) --------
__global__ __launch_bounds__(192) void k_add_ln768_2(
    u16* __restrict__ xb, const u16* __restrict__ y,
    const float* __restrict__ ybias,
    const float* __restrict__ g, const float* __restrict__ bta)
{
    const size_t SL = (size_t)MROWS*HID;
    int row = blockIdx.x;
    size_t base = (size_t)row * HID;
    int tid = threadIdx.x;
    int c = tid * 4;
    ushort4 xv = *(const ushort4*)(xb + base + c);
    ushort4 y0 = *(const ushort4*)(y + base + c);
    ushort4 y1 = *(const ushort4*)(y + SL + base + c);
    float4 bb = *(const float4*)(ybias + c);
    float v0 = b2f(xv.x)+b2f(y0.x)+b2f(y1.x)+bb.x;
    float v1 = b2f(xv.y)+b2f(y0.y)+b2f(y1.y)+bb.y;
    float v2 = b2f(xv.z)+b2f(y0.z)+b2f(y1.z)+bb.z;
    float v3 = b2f(xv.w)+b2f(y0.w)+b2f(y1.w)+bb.w;
    float sum = v0+v1+v2+v3;
    float sq  = v0*v0+v1*v1+v2*v2+v3*v3;
    #pragma unroll
    for(int off=32; off; off>>=1){ sum+=__shfl_xor(sum,off); sq+=__shfl_xor(sq,off); }
    __shared__ float s1[3], s2[3];
    int w = tid>>6;
    if((tid&63)==0){ s1[w]=sum; s2[w]=sq; }
    __syncthreads();
    sum = s1[0]+s1[1]+s1[2];
    sq  = s2[0]+s2[1]+s2[2];
    float m = sum*(1.f/768.f);
    float var = sq*(1.f/768.f) - m*m;
    float r = rsqrtf(var+LN_EPS);
    float4 gv = *(const float4*)(g + c);
    float4 bv = *(const float4*)(bta + c);
    ushort4 o;
    o.x = f2b((v0-m)*r*gv.x + bv.x);
    o.y = f2b((v1-m)*r*gv.y + bv.y);
    o.z = f2b((v2-m)*r*gv.z + bv.z);
    o.w = f2b((v3-m)*r*gv.w + bv.w);
    *(ushort4*)(xb + base + c) = o;
}

// ------ loss: zout given as 2 bf16 split-K slices (stride MROWS*EMB) -------
// h = LN(slice0 + slice1 + out_b); pos = <z,h>, neg = <LN(emb[neg]),h>
__global__ __launch_bounds__(256) void k_loss(
    const u16* __restrict__ zs, const float* __restrict__ z,
    const int* __restrict__ neg_ids, const float* __restrict__ emb,
    const float* __restrict__ outb,
    const float* __restrict__ eg, const float* __restrict__ eb,
    const float* __restrict__ og, const float* __restrict__ ob,
    float* __restrict__ loss)
{
    const size_t SL2 = (size_t)MROWS*EMB;
    int wv = threadIdx.x >> 6, lane = threadIdx.x & 63;
    int it0 = blockIdx.x*16 + wv*4;       // first of 4 items for this wave
    float h0r[4], h1r[4], z0[4], z1[4], ee0[4], ee1[4];
    #pragma unroll
    for(int i=0;i<4;i++){
        int it = it0 + i;
        int t = it >> 2, b = it & 3;
        int s = t + CW + 1;
        size_t hb = (size_t)(s*B_DIM+b)*EMB;
        h0r[i] = b2f(zs[hb+lane])    + b2f(zs[SL2+hb+lane])    + outb[lane];
        h1r[i] = b2f(zs[hb+lane+64]) + b2f(zs[SL2+hb+lane+64]) + outb[lane+64];
        z0[i]  = z[hb+lane];    z1[i]  = z[hb+lane+64];
        int nid = neg_ids[it];
        const float* e = emb + (size_t)nid*EMB;
        ee0[i] = e[lane]; ee1[i] = e[lane+64];
    }
    float local = 0.f;
    #pragma unroll
    for(int i=0;i<4;i++){
        float hsum = h0r[i]+h1r[i], hsq = h0r[i]*h0r[i]+h1r[i]*h1r[i];
        float esum = ee0[i]+ee1[i], esq = ee0[i]*ee0[i]+ee1[i]*ee1[i];
        #pragma unroll
        for(int off=32; off; off>>=1){
            hsum += __shfl_xor(hsum,off);
            hsq  += __shfl_xor(hsq,off);
            esum += __shfl_xor(esum,off);
            esq  += __shfl_xor(esq,off);
        }
        float hm = hsum*(1.f/128.f), hvar = hsq*(1.f/128.f)-hm*hm, hr = rsqrtf(hvar+LN_EPS);
        float h0 = (h0r[i]-hm)*hr*og[lane]    + ob[lane];
        float h1 = (h1r[i]-hm)*hr*og[lane+64] + ob[lane+64];
        float em = esum*(1.f/128.f), evar = esq*(1.f/128.f)-em*em, er = rsqrtf(evar+LN_EPS);
        float zn0 = (ee0[i]-em)*er*eg[lane]    + eb[lane];
        float zn1 = (ee1[i]-em)*er*eg[lane+64] + eb[lane+64];
        float pv = z0[i]*h0 + z1[i]*h1;
        float nv = zn0*h0 + zn1*h1;
        #pragma unroll
        for(int off=32; off; off>>=1){
            pv += __shfl_xor(pv,off);
            nv += __shfl_xor(nv,off);
        }
        if(lane==0) local += softplus_f(-pv) + softplus_f(nv);
    }
    __shared__ float ls[4];
    if(lane==0) ls[wv] = local;
    __syncthreads();
    if(threadIdx.x==0){
        float v = ls[0]+ls[1]+ls[2]+ls[3];
        atomicAdd(loss, v * (1.0f/(2.0f*T_LEN*B_DIM)));
    }
}

static inline int cvt_grid(size_t n){ return (int)((n/4 + 255)/256); }

extern "C" void kernel_launch(void* const* d_in, const int* in_sizes, int n_in,
                              void* d_out, int out_size, void* d_ws, size_t ws_size,
                              hipStream_t stream) {
    const int*   seq      = (const int*)  d_in[0];
    const int*   neg_ids  = (const int*)  d_in[1];
    const float* emb      = (const float*)d_in[2];
    const float* emb_ln_g = (const float*)d_in[3];
    const float* emb_ln_b = (const float*)d_in[4];
    const float* proj_w   = (const float*)d_in[5];
    const float* proj_b   = (const float*)d_in[6];
    const float* wqkv     = (const float*)d_in[7];
    const float* bqkv     = (const float*)d_in[8];
    const float* wo       = (const float*)d_in[9];
    const float* bo       = (const float*)d_in[10];
    const float* ln1_g    = (const float*)d_in[11];
    const float* ln1_b    = (const float*)d_in[12];
    const float* w1       = (const float*)d_in[13];
    const float* b1       = (const float*)d_in[14];
    const float* w2       = (const float*)d_in[15];
    const float* b2       = (const float*)d_in[16];
    const float* ln2_g    = (const float*)d_in[17];
    const float* ln2_b    = (const float*)d_in[18];
    const float* out_w    = (const float*)d_in[19];
    const float* out_b    = (const float*)d_in[20];
    const float* out_ln_g = (const float*)d_in[21];
    const float* out_ln_b = (const float*)d_in[22];

    // weight element counts
    const size_t NPROJ = (size_t)HID*EMB;          // 98304
    const size_t NQKV  = (size_t)3*HID*HID;        // 1769472 per layer
    const size_t NWO   = (size_t)HID*HID;          // 589824
    const size_t NW1   = (size_t)4*HID*HID;        // 2359296
    const size_t NW2   = (size_t)4*HID*HID;        // 2359296
    const size_t NOUT  = (size_t)EMB*HID;          // 98304

    // ---- workspace carve (bytes) ----
    char* p = (char*)d_ws;
    float* pe   = (float*)p; p += (size_t)S_LEN*HID*4;     // 3.1 MB
    float* z    = (float*)p; p += (size_t)MROWS*EMB*4;     // 2.1 MB
    u16*  zs_b  = (u16*)p;   p += (size_t)2*MROWS*EMB*2;   // 2.1 MB (out slices)
    u16*  z_b   = (u16*)p;   p += (size_t)MROWS*EMB*2;     // 1.0 MB
    u16*  x_b   = (u16*)p;   p += (size_t)MROWS*HID*2;     // 6.3 MB
    u16*  at_b  = (u16*)p;   p += (size_t)MROWS*HID*2;     // 6.3 MB
    u16*  y_b   = (u16*)p;   p += (size_t)2*MROWS*HID*2;   // 12.6 MB (2 slices)
    u16*  big   = (u16*)p;   p += (size_t)MROWS*3072*2;    // 25.2 MB
    size_t act_bytes = (size_t)(p - (char*)d_ws);          // ~59 MB

    // full path: all weights converted once (54 MB); fallback: per-layer scratch
    size_t full_w_elems = NPROJ + NOUT + LAYERS*(NQKV + NWO + NW1 + NW2);
    bool full = ws_size >= act_bytes + full_w_elems*2;
    size_t fb_elems = NPROJ + NOUT + NQKV + NWO + NW1 + NW2;  // one layer + proj/out
    if(!full && ws_size < act_bytes + fb_elems*2) return;     // loud failure

    u16* wbase = (u16*)p;
    u16 *wp_proj, *wp_out, *wp_qkv0, *wp_wo0, *wp_w10, *wp_w20;
    size_t sq, so, s1o, s2o;   // per-layer strides in full mode
    if(full){
        u16* q0 = wbase;
        wp_proj = q0;                 q0 += NPROJ;
        wp_out  = q0;                 q0 += NOUT;
        wp_qkv0 = q0;                 q0 += LAYERS*NQKV;
        wp_wo0  = q0;                 q0 += LAYERS*NWO;
        wp_w10  = q0;                 q0 += LAYERS*NW1;
        wp_w20  = q0;                 q0 += LAYERS*NW2;
        sq = NQKV; so = NWO; s1o = NW1; s2o = NW2;
    } else {
        u16* q0 = wbase;
        wp_proj = q0;                 q0 += NPROJ;
        wp_out  = q0;                 q0 += NOUT;
        wp_qkv0 = q0;                 q0 += NQKV;
        wp_wo0  = q0;                 q0 += NWO;
        wp_w10  = q0;                 q0 += NW1;
        wp_w20  = q0;                 q0 += NW2;
        sq = so = s1o = s2o = 0;      // reuse same slots every layer
    }

    hipMemsetAsync(d_out, 0, sizeof(float), stream);

    k_pe<<<(S_LEN*HID+255)/256, 256, 0, stream>>>(pe);
    k_embed_ln<<<MROWS, 64, 0, stream>>>(seq, emb, emb_ln_g, emb_ln_b, z, z_b);

    k_cvt<<<cvt_grid(NPROJ), 256, 0, stream>>>(proj_w, wp_proj, (int)(NPROJ/4));
    k_cvt<<<cvt_grid(NOUT),  256, 0, stream>>>(out_w,  wp_out,  (int)(NOUT/4));
    if(full){
        k_cvt<<<cvt_grid(LAYERS*NQKV), 256, 0, stream>>>(wqkv, wp_qkv0, (int)(LAYERS*NQKV/4));
        k_cvt<<<cvt_grid(LAYERS*NWO),  256, 0, stream>>>(wo,   wp_wo0,  (int)(LAYERS*NWO/4));
        k_cvt<<<cvt_grid(LAYERS*NW1),  256, 0, stream>>>(w1,   wp_w10,  (int)(LAYERS*NW1/4));
        k_cvt<<<cvt_grid(LAYERS*NW2),  256, 0, stream>>>(w2,   wp_w20,  (int)(LAYERS*NW2/4));
    }

    // x_b = gelu(z @ proj_w^T + b) + pe   (bf16); K=128 -> BK=64, 2 steps
    k_mm<128,64,64,256,2,2,1,2,0,1><<<(768/64)*(MROWS/128), 256, 0, stream>>>(
        z_b, wp_proj, proj_b, nullptr, x_b, MROWS, HID, EMB, pe);

    for(int l=0; l<LAYERS; ++l){
        if(!full){
            k_cvt<<<cvt_grid(NQKV), 256, 0, stream>>>(wqkv + (size_t)l*NQKV, wp_qkv0, (int)(NQKV/4));
            k_cvt<<<cvt_grid(NWO),  256, 0, stream>>>(wo   + (size_t)l*NWO,  wp_wo0,  (int)(NWO/4));
            k_cvt<<<cvt_grid(NW1),  256, 0, stream>>>(w1   + (size_t)l*NW1,  wp_w10,  (int)(NW1/4));
            k_cvt<<<cvt_grid(NW2),  256, 0, stream>>>(w2   + (size_t)l*NW2,  wp_w20,  (int)(NW2/4));
        }
        // qkv: 256x128 tile, BK=32, 512 threads (4x2 waves, 64x64 each), 2-buf
        k_mm<256,128,32,512,2,2,1,0,0,1><<<(2304/128)*(MROWS/256), 512, 0, stream>>>(
            x_b, wp_qkv0 + (size_t)l*sq, bqkv + l*2304, nullptr, big, MROWS, 2304, HID, nullptr);
        k_attn<<<(S_LEN/16)*B_DIM*NHEAD/4, 256, 0, stream>>>(big, at_b);
        // wo: split-K=2, BK=64, bf16 slices into y_b; bias folded into add_ln
        k_mm<128,64,64,256,2,2,2,3,0,0><<<(768/64)*(MROWS/128)*2, 256, 0, stream>>>(
            at_b, wp_wo0 + (size_t)l*so, nullptr, nullptr, y_b, MROWS, HID, HID, nullptr);
        k_add_ln768_2<<<MROWS, 192, 0, stream>>>(x_b, y_b, bo + l*HID,
                                                 ln1_g + l*HID, ln1_b + l*HID);
        // ff1: 256x128 tile, BK=32, 512 threads, 2-buf
        k_mm<256,128,32,512,2,2,1,1,0,1><<<(3072/128)*(MROWS/256), 512, 0, stream>>>(
            x_b, wp_w10 + (size_t)l*s1o, b1 + l*3072, nullptr, big, MROWS, 3072, HID, nullptr);
        // ff2: split-K=2, BK=64, bf16 slices into y_b
        k_mm<128,64,64,256,2,2,2,3,0,0><<<(768/64)*(MROWS/128)*2, 256, 0, stream>>>(
            big, wp_w20 + (size_t)l*s2o, nullptr, nullptr, y_b, MROWS, HID, 3072, nullptr);
        k_add_ln768_2<<<MROWS, 192, 0, stream>>>(x_b, y_b, b2 + l*HID,
                                                 ln2_g + l*HID, ln2_b + l*HID);
    }
    // out: split-K=2, BM=64 -> 256 blocks; bf16 slices; bias+LN fused in k_loss
    k_mm<64,64,64,256,2,2,2,3,0,0><<<(EMB/64)*(MROWS/64)*2, 256, 0, stream>>>(
        x_b, wp_out, nullptr, nullptr, zs_b, MROWS, EMB, HID, nullptr);
    k_loss<<<(T_LEN*B_DIM)/16, 256, 0, stream>>>(zs_b, z, neg_ids, emb, out_b,
                                                 emb_ln_g, emb_ln_b, out_ln_g, out_ln_b,
                                                 (float*)d_out);
}

// Round 20
// 537.511 us; speedup vs baseline: 1.0966x; 1.0966x over previous
//
#include <hip/hip_runtime.h>
#include <hip/hip_bf16.h>
#include <math.h>

#define S_LEN 1024
#define B_DIM 4
#define EMB 128
#define HID 768
#define LAYERS 4
#define CW 3
#define NHEAD 12
#define HDIM 64
#define T_LEN (S_LEN - 4*CW)   // 1012
#define LN_EPS 1e-5f
#define MROWS (S_LEN*B_DIM)    // 4096

typedef unsigned short u16;
typedef __attribute__((ext_vector_type(8))) __bf16 bf16x8;
typedef __attribute__((ext_vector_type(4))) float f32x4;

__device__ __forceinline__ u16 f2b(float f){
    unsigned u = __float_as_uint(f);
    u += 0x7fff + ((u >> 16) & 1);          // round-to-nearest-even
    return (u16)(u >> 16);
}
__device__ __forceinline__ float b2f(u16 h){
    return __uint_as_float(((unsigned)h) << 16);
}
__device__ __forceinline__ float gelu_exact(float x){
    return 0.5f * x * (1.0f + erff(x * 0.70710678118654752f));
}
__device__ __forceinline__ float softplus_f(float x){
    return fmaxf(x, 0.0f) + log1pf(expf(-fabsf(x)));
}
template<int N> __device__ __forceinline__ void waitcnt_vm(){
    if constexpr(N==0) asm volatile("s_waitcnt vmcnt(0)" ::: "memory");
    else if constexpr(N==2) asm volatile("s_waitcnt vmcnt(2)" ::: "memory");
    else if constexpr(N==3) asm volatile("s_waitcnt vmcnt(3)" ::: "memory");
    else if constexpr(N==4) asm volatile("s_waitcnt vmcnt(4)" ::: "memory");
    else if constexpr(N==6) asm volatile("s_waitcnt vmcnt(6)" ::: "memory");
    else if constexpr(N==8) asm volatile("s_waitcnt vmcnt(8)" ::: "memory");
    else if constexpr(N==12) asm volatile("s_waitcnt vmcnt(12)" ::: "memory");
}

// ---------------- f32 -> bf16 weight conversion ----------------
__global__ void k_cvt(const float* __restrict__ w, u16* __restrict__ o, int n4){
    int i = blockIdx.x*256 + threadIdx.x;
    if(i >= n4) return;
    float4 v = *(const float4*)(w + (size_t)i*4);
    ushort4 t; t.x=f2b(v.x); t.y=f2b(v.y); t.z=f2b(v.z); t.w=f2b(v.w);
    *(ushort4*)(o + (size_t)i*4) = t;
}

// ---------------- positional encoding table (S, HID) ----------------
__global__ void k_pe(float* __restrict__ pe){
    int idx = blockIdx.x*256 + threadIdx.x;
    if(idx >= S_LEN*HID) return;
    int s = idx / HID, c = idx % HID;
    int i2 = (c >> 1) * 2;
    float freq = expf(-(float)i2 * (logf(10000.0f) / (float)HID));
    float ang = (float)s * freq;
    pe[idx] = (c & 1) ? cosf(ang) : sinf(ang);
}

// ---------------- z = LN(emb_table[seq^T]) : f32 + bf16 copies ----------------
__global__ void k_embed_ln(const int* __restrict__ seq,
                           const float* __restrict__ emb,
                           const float* __restrict__ g,
                           const float* __restrict__ bta,
                           float* __restrict__ z, u16* __restrict__ zb){
    int row = blockIdx.x;
    int s = row >> 2, b = row & 3;
    int tok = seq[b*S_LEN + s];
    const float* e = emb + (size_t)tok * EMB;
    int lane = threadIdx.x;
    float v0 = e[lane], v1 = e[lane+64];
    float sum = v0+v1, sq = v0*v0+v1*v1;
    #pragma unroll
    for(int off=32; off; off>>=1){ sum += __shfl_xor(sum,off); sq += __shfl_xor(sq,off); }
    float m = sum * (1.0f/128.0f);
    float var = sq*(1.0f/128.0f) - m*m;
    float r = rsqrtf(var + LN_EPS);
    size_t base = (size_t)row*EMB;
    float o0 = (v0-m)*r*g[lane]    + bta[lane];
    float o1 = (v1-m)*r*g[lane+64] + bta[lane+64];
    z[base+lane] = o0; z[base+lane+64] = o1;
    zb[base+lane] = f2b(o0); zb[base+lane+64] = f2b(o1);
}

// ---------------- MFMA GEMM: C[M,N] = A_bf16[M,K] * B_bf16[N,K]^T (+bias) ---
// BMxBN tile, BK in {32,64}, THR threads, WC wave-columns, NBUF LDS buffers,
// SK-way split-K.
// NBUF=3: prefetch-1, single barrier/K-step. NBUF=2: 2 barriers (WAR).
// BK=32 chunk swizzle u^((row>>1)&3); BK=64: u^(row&7). Swizzle applied on
// pre-swizzled global source AND ds_read side (rule #21).
// Counted s_waitcnt vmcnt keeps prefetched tile in flight across barriers.
// s_setprio(1) around MFMA cluster (T5).
// EPI: 0 +bias, 1 gelu(+bias), 2 gelu(+bias)+pe,
//      3 slice-partial bf16 write (no bias): Cb[slice*M*N + row*N + col].
template<int BM, int BN, int BK, int THR, int WC, int NBUF, int SK,
         int EPI, int WF, int WB>
__global__ __launch_bounds__(THR) void k_mm(
    const u16*  __restrict__ A,
    const u16*  __restrict__ Bw,
    const float* __restrict__ bias,
    float* __restrict__ Cf, u16* __restrict__ Cb,
    int M, int N, int K, const float* __restrict__ pe)
{
    constexpr int NW = THR/64;
    constexpr int WROW = NW/WC;
    constexpr int WM = BM/WROW, WN = BN/WC, MR = WM/16, NR = WN/16;
    constexpr int ROWB = BK*2;                 // bytes per LDS row
    constexpr int CM = ROWB/16 - 1;            // chunk mask (3 or 7)
    constexpr int RA = (BM*ROWB)/(THR*16);     // stage rounds for A (>=1)
    constexpr int RB = (BN*ROWB)/(THR*16);     // stage rounds for B (>=1)
    constexpr int IC = RA + RB;                // gload_lds issues/thread/tile
    static_assert(RA >= 1 && RB >= 1, "tile too small for THR");
    __shared__ u16 Al[NBUF][BM*BK];
    __shared__ u16 Bl[NBUF][BN*BK];
    int tid = threadIdx.x;
    int wave = tid >> 6, lane = tid & 63;

    // 1D grid: slice-slowest / rows-slow / cols-fast + bijective XCD swizzle
    int nbx = N / BN, nby = M / BM, nwg = nbx * nby * SK;
    int bid = blockIdx.x;
    int q = nwg >> 3, rm = nwg & 7, xcd = bid & 7, off = bid >> 3;
    int sbid = (xcd < rm ? xcd*(q+1) : rm*(q+1) + (xcd-rm)*q) + off;
    int slice = sbid / (nbx*nby);
    int rb2 = sbid % (nbx*nby);
    int row0 = (rb2 / nbx) * BM, col0 = (rb2 % nbx) * BN;
    int kb = slice * (K / SK);

    int wr = wave / WC, wc = wave % WC;
    int lr = lane & 15, lk = lane >> 4;

    f32x4 acc[MR][NR];
    #pragma unroll
    for(int m=0;m<MR;m++)
        #pragma unroll
        for(int n=0;n<NR;n++) acc[m][n] = (f32x4){0.f,0.f,0.f,0.f};

    const char* Abase = (const char*)A;
    const char* Bbase = (const char*)Bw;

    auto swz = [](int u, int rr)->int{
        if constexpr(BK==32) return u ^ ((rr>>1)&3);
        else                 return u ^ (rr & CM);
    };
    auto stage = [&](int buf, int k0){
        #pragma unroll
        for(int i=0;i<RA;i++){
            int p = i*(THR*16) + tid*16;               // byte offset in tile
            int rr = p / ROWB, u = (p >> 4) & CM;
            int us = swz(u, rr);
            const char* g = Abase + ((size_t)(row0+rr)*K + k0)*2 + us*16;
            void* l = (char*)&Al[buf][0] + i*(THR*16) + wave*1024;  // wave-uniform
            __builtin_amdgcn_global_load_lds(
                (const __attribute__((address_space(1))) void*)g,
                (__attribute__((address_space(3))) void*)l, 16, 0, 0);
        }
        #pragma unroll
        for(int i=0;i<RB;i++){
            int p = i*(THR*16) + tid*16;
            int rr = p / ROWB, u = (p >> 4) & CM;
            int us = swz(u, rr);
            const char* g = Bbase + ((size_t)(col0+rr)*K + k0)*2 + us*16;
            void* l = (char*)&Bl[buf][0] + i*(THR*16) + wave*1024;
            __builtin_amdgcn_global_load_lds(
                (const __attribute__((address_space(1))) void*)g,
                (__attribute__((address_space(3))) void*)l, 16, 0, 0);
        }
    };

    int nt = (K / SK) / BK;
    stage(0, kb);
    int cur = 0;
    for(int t=0; t<nt; ++t){
        if constexpr(NBUF==3){
            // prefetch-1, single barrier: write (t+1)%3, reads t%3 / (t-1)%3
            int nxt = (cur==2) ? 0 : cur+1;
            if(t+1 < nt){ stage(nxt, kb + (t+1)*BK); waitcnt_vm<IC>(); }
            else        { waitcnt_vm<0>(); }
            __builtin_amdgcn_s_barrier();
            __builtin_amdgcn_sched_barrier(0);
        } else {
            if(t+1 < nt){ stage(cur^1, kb + (t+1)*BK); waitcnt_vm<IC>(); }
            else        { waitcnt_vm<0>(); }
            __builtin_amdgcn_s_barrier();
            __builtin_amdgcn_sched_barrier(0);
        }
        #pragma unroll
        for(int kk=0; kk<BK/32; ++kk){
            bf16x8 af[MR], bfr[NR];
            #pragma unroll
            for(int m=0;m<MR;m++){
                int ar = wr*WM + m*16 + lr;
                int c  = swz(kk*4 + lk, ar);
                af[m] = *(const bf16x8*)((const char*)&Al[cur][0] + ar*ROWB + (c<<4));
            }
            #pragma unroll
            for(int n=0;n<NR;n++){
                int br = wc*WN + n*16 + lr;
                int c  = swz(kk*4 + lk, br);
                bfr[n] = *(const bf16x8*)((const char*)&Bl[cur][0] + br*ROWB + (c<<4));
            }
            __builtin_amdgcn_s_setprio(1);
            #pragma unroll
            for(int m=0;m<MR;m++)
                #pragma unroll
                for(int n=0;n<NR;n++)
                    acc[m][n] = __builtin_amdgcn_mfma_f32_16x16x32_bf16(af[m], bfr[n], acc[m][n], 0, 0, 0);
            __builtin_amdgcn_s_setprio(0);
        }
        if constexpr(NBUF==3){
            cur = (cur==2) ? 0 : cur+1;     // no trailing barrier
        } else {
            __builtin_amdgcn_s_barrier();   // WAR barrier for 2-buffer
            cur ^= 1;
        }
    }
    // epilogue: C/D layout col=lane&15, row=(lane>>4)*4+j
    #pragma unroll
    for(int m=0;m<MR;m++){
        #pragma unroll
        for(int n=0;n<NR;n++){
            #pragma unroll
            for(int j=0;j<4;j++){
                int row = row0 + wr*WM + m*16 + lk*4 + j;
                int col = col0 + wc*WN + n*16 + lr;
                float v = acc[m][n][j];
                if constexpr(EPI==3){
                    Cb[(size_t)slice*M*N + (size_t)row*N + col] = f2b(v);
                } else {
                    v += bias[col];
                    if(EPI==1) v = gelu_exact(v);
                    if(EPI==2) v = gelu_exact(v) + pe[(size_t)(row>>2)*HID + col];
                    if(WF) Cf[(size_t)row*N + col] = v;
                    if(WB) Cb[(size_t)row*N + col] = f2b(v);
                }
            }
        }
    }
}

// ---------------- banded attention, MFMA QK^T ----------------
__global__ __launch_bounds__(256) void k_attn(const u16* __restrict__ qkv,
                                              u16* __restrict__ out){
    __shared__ float P[4][16][36];
    int wv = threadIdx.x >> 6;
    int lane = threadIdx.x & 63;
    int wid = (blockIdx.x << 2) + wv;      // 0..3071
    int h = wid % NHEAD;
    int b = (wid / NHEAD) & 3;
    int s0 = (wid / (NHEAD*B_DIM)) << 4;   // query tile base
    int lr = lane & 15, lk = lane >> 4;
    const int RS = 3*HID;                  // 2304

    bf16x8 qf[2], kf[2][2];
    #pragma unroll
    for(int kk=0;kk<2;kk++)
        qf[kk] = *(const bf16x8*)(qkv + (size_t)((s0+lr)*B_DIM + b)*RS + h*HDIM + kk*32 + lk*8);
    #pragma unroll
    for(int c=0;c<2;c++){
        int t = s0 + c*16 + lr; if(t > S_LEN-1) t = S_LEN-1;
        #pragma unroll
        for(int kk=0;kk<2;kk++)
            kf[c][kk] = *(const bf16x8*)(qkv + (size_t)(t*B_DIM + b)*RS + HID + h*HDIM + kk*32 + lk*8);
    }
    f32x4 acc0 = {0.f,0.f,0.f,0.f}, acc1 = {0.f,0.f,0.f,0.f};
    #pragma unroll
    for(int kk=0;kk<2;kk++){
        acc0 = __builtin_amdgcn_mfma_f32_16x16x32_bf16(qf[kk], kf[0][kk], acc0, 0,0,0);
        acc1 = __builtin_amdgcn_mfma_f32_16x16x32_bf16(qf[kk], kf[1][kk], acc1, 0,0,0);
    }
    float e0[4], e1[4], mx[4], sm[4];
    #pragma unroll
    for(int j=0;j<4;j++){
        int r = 4*lk + j;
        int g0 = lr - r, g1 = 16 + lr - r;
        bool a0 = (g0>=0) & (g0<=12) & (g0!=6);
        bool a1 = (g1>=0) & (g1<=12) & (g1!=6) & (s0+16+lr < S_LEN);
        e0[j] = a0 ? acc0[j]*0.125f : -INFINITY;
        e1[j] = a1 ? acc1[j]*0.125f : -INFINITY;
        mx[j] = fmaxf(e0[j], e1[j]);
    }
    #pragma unroll
    for(int off=1; off<16; off<<=1){
        #pragma unroll
        for(int j=0;j<4;j++) mx[j] = fmaxf(mx[j], __shfl_xor(mx[j], off));
    }
    #pragma unroll
    for(int j=0;j<4;j++){
        e0[j] = expf(e0[j]-mx[j]);
        e1[j] = expf(e1[j]-mx[j]);
        sm[j] = e0[j]+e1[j];
    }
    #pragma unroll
    for(int off=1; off<16; off<<=1){
        #pragma unroll
        for(int j=0;j<4;j++) sm[j] += __shfl_xor(sm[j], off);
    }
    #pragma unroll
    for(int j=0;j<4;j++){
        float inv = 1.0f/sm[j];
        int r = 4*lk + j;
        P[wv][r][lr]      = e0[j]*inv;
        P[wv][r][16+lr]   = e1[j]*inv;
    }
    float o[16];
    #pragma unroll
    for(int r=0;r<16;r++) o[r] = 0.f;
    #pragma unroll
    for(int g4=0; g4<32; g4+=4){
        float vr[4];
        #pragma unroll
        for(int qq=0;qq<4;qq++){
            int t = s0 + g4 + qq; if(t > S_LEN-1) t = S_LEN-1;
            vr[qq] = b2f(qkv[(size_t)(t*B_DIM + b)*RS + 2*HID + h*HDIM + lane]);
        }
        #pragma unroll
        for(int r=0;r<16;r++){
            f32x4 w = *(const f32x4*)&P[wv][r][g4];
            o[r] = fmaf(w[0], vr[0], fmaf(w[1], vr[1], fmaf(w[2], vr[2], fmaf(w[3], vr[3], o[r]))));
        }
    }
    #pragma unroll
    for(int r=0;r<16;r++)
        out[(size_t)((s0+r)*B_DIM + b)*HID + h*HDIM + lane] = f2b(o[r]);
}

// ------- xb = LN(xb + y0 + y1 + ybias), wave-per-row (no LDS/barrier) ------
__global__ __launch_bounds__(256) void k_add_ln768_2(
    u16* __restrict__ xb, const u16* __restrict__ y,
    const float* __restrict__ ybias,
    const float* __restrict__ g, const float* __restrict__ bta)
{
    const size_t SL = (size_t)MROWS*HID;
    int wv = threadIdx.x >> 6, lane = threadIdx.x & 63;
    int row = (blockIdx.x << 2) + wv;
    size_t base = (size_t)row * HID;
    float v[12]; float sum = 0.f, sq = 0.f;
    #pragma unroll
    for(int i=0;i<3;i++){
        int c = i*256 + lane*4;
        ushort4 xv = *(const ushort4*)(xb + base + c);
        ushort4 y0 = *(const ushort4*)(y + base + c);
        ushort4 y1 = *(const ushort4*)(y + SL + base + c);
        float4 bb = *(const float4*)(ybias + c);
        float a0 = b2f(xv.x)+b2f(y0.x)+b2f(y1.x)+bb.x;
        float a1 = b2f(xv.y)+b2f(y0.y)+b2f(y1.y)+bb.y;
        float a2 = b2f(xv.z)+b2f(y0.z)+b2f(y1.z)+bb.z;
        float a3 = b2f(xv.w)+b2f(y0.w)+b2f(y1.w)+bb.w;
        v[i*4+0]=a0; v[i*4+1]=a1; v[i*4+2]=a2; v[i*4+3]=a3;
        sum += a0+a1+a2+a3;
        sq  += a0*a0+a1*a1+a2*a2+a3*a3;
    }
    #pragma unroll
    for(int off=32; off; off>>=1){ sum+=__shfl_xor(sum,off); sq+=__shfl_xor(sq,off); }
    float m = sum*(1.f/768.f);
    float var = sq*(1.f/768.f) - m*m;
    float r = rsqrtf(var+LN_EPS);
    #pragma unroll
    for(int i=0;i<3;i++){
        int c = i*256 + lane*4;
        float4 gv = *(const float4*)(g + c);
        float4 bv = *(const float4*)(bta + c);
        ushort4 o;
        o.x = f2b((v[i*4+0]-m)*r*gv.x + bv.x);
        o.y = f2b((v[i*4+1]-m)*r*gv.y + bv.y);
        o.z = f2b((v[i*4+2]-m)*r*gv.z + bv.z);
        o.w = f2b((v[i*4+3]-m)*r*gv.w + bv.w);
        *(ushort4*)(xb + base + c) = o;
    }
}

// ------ loss: zout given as 2 bf16 split-K slices (stride MROWS*EMB) -------
// h = LN(slice0 + slice1 + out_b); pos = <z,h>, neg = <LN(emb[neg]),h>
__global__ __launch_bounds__(256) void k_loss(
    const u16* __restrict__ zs, const float* __restrict__ z,
    const int* __restrict__ neg_ids, const float* __restrict__ emb,
    const float* __restrict__ outb,
    const float* __restrict__ eg, const float* __restrict__ eb,
    const float* __restrict__ og, const float* __restrict__ ob,
    float* __restrict__ loss)
{
    const size_t SL2 = (size_t)MROWS*EMB;
    int wv = threadIdx.x >> 6, lane = threadIdx.x & 63;
    int it0 = blockIdx.x*16 + wv*4;       // first of 4 items for this wave
    float h0r[4], h1r[4], z0[4], z1[4], ee0[4], ee1[4];
    #pragma unroll
    for(int i=0;i<4;i++){
        int it = it0 + i;
        int t = it >> 2, b = it & 3;
        int s = t + CW + 1;
        size_t hb = (size_t)(s*B_DIM+b)*EMB;
        h0r[i] = b2f(zs[hb+lane])    + b2f(zs[SL2+hb+lane])    + outb[lane];
        h1r[i] = b2f(zs[hb+lane+64]) + b2f(zs[SL2+hb+lane+64]) + outb[lane+64];
        z0[i]  = z[hb+lane];    z1[i]  = z[hb+lane+64];
        int nid = neg_ids[it];
        const float* e = emb + (size_t)nid*EMB;
        ee0[i] = e[lane]; ee1[i] = e[lane+64];
    }
    float local = 0.f;
    #pragma unroll
    for(int i=0;i<4;i++){
        float hsum = h0r[i]+h1r[i], hsq = h0r[i]*h0r[i]+h1r[i]*h1r[i];
        float esum = ee0[i]+ee1[i], esq = ee0[i]*ee0[i]+ee1[i]*ee1[i];
        #pragma unroll
        for(int off=32; off; off>>=1){
            hsum += __shfl_xor(hsum,off);
            hsq  += __shfl_xor(hsq,off);
            esum += __shfl_xor(esum,off);
            esq  += __shfl_xor(esq,off);
        }
        float hm = hsum*(1.f/128.f), hvar = hsq*(1.f/128.f)-hm*hm, hr = rsqrtf(hvar+LN_EPS);
        float h0 = (h0r[i]-hm)*hr*og[lane]    + ob[lane];
        float h1 = (h1r[i]-hm)*hr*og[lane+64] + ob[lane+64];
        float em = esum*(1.f/128.f), evar = esq*(1.f/128.f)-em*em, er = rsqrtf(evar+LN_EPS);
        float zn0 = (ee0[i]-em)*er*eg[lane]    + eb[lane];
        float zn1 = (ee1[i]-em)*er*eg[lane+64] + eb[lane+64];
        float pv = z0[i]*h0 + z1[i]*h1;
        float nv = zn0*h0 + zn1*h1;
        #pragma unroll
        for(int off=32; off; off>>=1){
            pv += __shfl_xor(pv,off);
            nv += __shfl_xor(nv,off);
        }
        if(lane==0) local += softplus_f(-pv) + softplus_f(nv);
    }
    __shared__ float ls[4];
    if(lane==0) ls[wv] = local;
    __syncthreads();
    if(threadIdx.x==0){
        float v = ls[0]+ls[1]+ls[2]+ls[3];
        atomicAdd(loss, v * (1.0f/(2.0f*T_LEN*B_DIM)));
    }
}

static inline int cvt_grid(size_t n){ return (int)((n/4 + 255)/256); }

extern "C" void kernel_launch(void* const* d_in, const int* in_sizes, int n_in,
                              void* d_out, int out_size, void* d_ws, size_t ws_size,
                              hipStream_t stream) {
    const int*   seq      = (const int*)  d_in[0];
    const int*   neg_ids  = (const int*)  d_in[1];
    const float* emb      = (const float*)d_in[2];
    const float* emb_ln_g = (const float*)d_in[3];
    const float* emb_ln_b = (const float*)d_in[4];
    const float* proj_w   = (const float*)d_in[5];
    const float* proj_b   = (const float*)d_in[6];
    const float* wqkv     = (const float*)d_in[7];
    const float* bqkv     = (const float*)d_in[8];
    const float* wo       = (const float*)d_in[9];
    const float* bo       = (const float*)d_in[10];
    const float* ln1_g    = (const float*)d_in[11];
    const float* ln1_b    = (const float*)d_in[12];
    const float* w1       = (const float*)d_in[13];
    const float* b1       = (const float*)d_in[14];
    const float* w2       = (const float*)d_in[15];
    const float* b2       = (const float*)d_in[16];
    const float* ln2_g    = (const float*)d_in[17];
    const float* ln2_b    = (const float*)d_in[18];
    const float* out_w    = (const float*)d_in[19];
    const float* out_b    = (const float*)d_in[20];
    const float* out_ln_g = (const float*)d_in[21];
    const float* out_ln_b = (const float*)d_in[22];

    // weight element counts
    const size_t NPROJ = (size_t)HID*EMB;          // 98304
    const size_t NQKV  = (size_t)3*HID*HID;        // 1769472 per layer
    const size_t NWO   = (size_t)HID*HID;          // 589824
    const size_t NW1   = (size_t)4*HID*HID;        // 2359296
    const size_t NW2   = (size_t)4*HID*HID;        // 2359296
    const size_t NOUT  = (size_t)EMB*HID;          // 98304

    // ---- workspace carve (bytes) ----
    char* p = (char*)d_ws;
    float* pe   = (float*)p; p += (size_t)S_LEN*HID*4;     // 3.1 MB
    float* z    = (float*)p; p += (size_t)MROWS*EMB*4;     // 2.1 MB
    u16*  zs_b  = (u16*)p;   p += (size_t)2*MROWS*EMB*2;   // 2.1 MB (out slices)
    u16*  z_b   = (u16*)p;   p += (size_t)MROWS*EMB*2;     // 1.0 MB
    u16*  x_b   = (u16*)p;   p += (size_t)MROWS*HID*2;     // 6.3 MB
    u16*  at_b  = (u16*)p;   p += (size_t)MROWS*HID*2;     // 6.3 MB
    u16*  y_b   = (u16*)p;   p += (size_t)2*MROWS*HID*2;   // 12.6 MB (2 slices)
    u16*  big   = (u16*)p;   p += (size_t)MROWS*3072*2;    // 25.2 MB
    size_t act_bytes = (size_t)(p - (char*)d_ws);          // ~59 MB

    // full path: all weights converted once (54 MB); fallback: per-layer scratch
    size_t full_w_elems = NPROJ + NOUT + LAYERS*(NQKV + NWO + NW1 + NW2);
    bool full = ws_size >= act_bytes + full_w_elems*2;
    size_t fb_elems = NPROJ + NOUT + NQKV + NWO + NW1 + NW2;  // one layer + proj/out
    if(!full && ws_size < act_bytes + fb_elems*2) return;     // loud failure

    u16* wbase = (u16*)p;
    u16 *wp_proj, *wp_out, *wp_qkv0, *wp_wo0, *wp_w10, *wp_w20;
    size_t sq, so, s1o, s2o;   // per-layer strides in full mode
    if(full){
        u16* q0 = wbase;
        wp_proj = q0;                 q0 += NPROJ;
        wp_out  = q0;                 q0 += NOUT;
        wp_qkv0 = q0;                 q0 += LAYERS*NQKV;
        wp_wo0  = q0;                 q0 += LAYERS*NWO;
        wp_w10  = q0;                 q0 += LAYERS*NW1;
        wp_w20  = q0;                 q0 += LAYERS*NW2;
        sq = NQKV; so = NWO; s1o = NW1; s2o = NW2;
    } else {
        u16* q0 = wbase;
        wp_proj = q0;                 q0 += NPROJ;
        wp_out  = q0;                 q0 += NOUT;
        wp_qkv0 = q0;                 q0 += NQKV;
        wp_wo0  = q0;                 q0 += NWO;
        wp_w10  = q0;                 q0 += NW1;
        wp_w20  = q0;                 q0 += NW2;
        sq = so = s1o = s2o = 0;      // reuse same slots every layer
    }

    hipMemsetAsync(d_out, 0, sizeof(float), stream);

    k_pe<<<(S_LEN*HID+255)/256, 256, 0, stream>>>(pe);
    k_embed_ln<<<MROWS, 64, 0, stream>>>(seq, emb, emb_ln_g, emb_ln_b, z, z_b);

    k_cvt<<<cvt_grid(NPROJ), 256, 0, stream>>>(proj_w, wp_proj, (int)(NPROJ/4));
    k_cvt<<<cvt_grid(NOUT),  256, 0, stream>>>(out_w,  wp_out,  (int)(NOUT/4));
    if(full){
        k_cvt<<<cvt_grid(LAYERS*NQKV), 256, 0, stream>>>(wqkv, wp_qkv0, (int)(LAYERS*NQKV/4));
        k_cvt<<<cvt_grid(LAYERS*NWO),  256, 0, stream>>>(wo,   wp_wo0,  (int)(LAYERS*NWO/4));
        k_cvt<<<cvt_grid(LAYERS*NW1),  256, 0, stream>>>(w1,   wp_w10,  (int)(LAYERS*NW1/4));
        k_cvt<<<cvt_grid(LAYERS*NW2),  256, 0, stream>>>(w2,   wp_w20,  (int)(LAYERS*NW2/4));
    }

    // x_b = gelu(z @ proj_w^T + b) + pe   (bf16); K=128 -> BK=64, 2 steps
    k_mm<128,64,64,256,2,2,1,2,0,1><<<(768/64)*(MROWS/128), 256, 0, stream>>>(
        z_b, wp_proj, proj_b, nullptr, x_b, MROWS, HID, EMB, pe);

    for(int l=0; l<LAYERS; ++l){
        if(!full){
            k_cvt<<<cvt_grid(NQKV), 256, 0, stream>>>(wqkv + (size_t)l*NQKV, wp_qkv0, (int)(NQKV/4));
            k_cvt<<<cvt_grid(NWO),  256, 0, stream>>>(wo   + (size_t)l*NWO,  wp_wo0,  (int)(NWO/4));
            k_cvt<<<cvt_grid(NW1),  256, 0, stream>>>(w1   + (size_t)l*NW1,  wp_w10,  (int)(NW1/4));
            k_cvt<<<cvt_grid(NW2),  256, 0, stream>>>(w2   + (size_t)l*NW2,  wp_w20,  (int)(NW2/4));
        }
        // qkv: 128x128 tile, BK=32, 512 threads (2x4 waves), 3-buf single-barrier
        k_mm<128,128,32,512,4,3,1,0,0,1><<<(2304/128)*(MROWS/128), 512, 0, stream>>>(
            x_b, wp_qkv0 + (size_t)l*sq, bqkv + l*2304, nullptr, big, MROWS, 2304, HID, nullptr);
        k_attn<<<(S_LEN/16)*B_DIM*NHEAD/4, 256, 0, stream>>>(big, at_b);
        // wo: split-K=2, BK=64, bf16 slices into y_b; bias folded into add_ln
        k_mm<128,64,64,256,2,2,2,3,0,0><<<(768/64)*(MROWS/128)*2, 256, 0, stream>>>(
            at_b, wp_wo0 + (size_t)l*so, nullptr, nullptr, y_b, MROWS, HID, HID, nullptr);
        k_add_ln768_2<<<MROWS/4, 256, 0, stream>>>(x_b, y_b, bo + l*HID,
                                                   ln1_g + l*HID, ln1_b + l*HID);
        // ff1: 128x128 tile, BK=32, 512 threads, 3-buf single-barrier
        k_mm<128,128,32,512,4,3,1,1,0,1><<<(3072/128)*(MROWS/128), 512, 0, stream>>>(
            x_b, wp_w10 + (size_t)l*s1o, b1 + l*3072, nullptr, big, MROWS, 3072, HID, nullptr);
        // ff2: split-K=2, BK=64, bf16 slices into y_b
        k_mm<128,64,64,256,2,2,2,3,0,0><<<(768/64)*(MROWS/128)*2, 256, 0, stream>>>(
            big, wp_w20 + (size_t)l*s2o, nullptr, nullptr, y_b, MROWS, HID, 3072, nullptr);
        k_add_ln768_2<<<MROWS/4, 256, 0, stream>>>(x_b, y_b, b2 + l*HID,
                                                   ln2_g + l*HID, ln2_b + l*HID);
    }
    // out: split-K=2, BM=64 -> 256 blocks; bf16 slices; bias+LN fused in k_loss
    k_mm<64,64,64,256,2,2,2,3,0,0><<<(EMB/64)*(MROWS/64)*2, 256, 0, stream>>>(
        x_b, wp_out, nullptr, nullptr, zs_b, MROWS, EMB, HID, nullptr);
    k_loss<<<(T_LEN*B_DIM)/16, 256, 0, stream>>>(zs_b, z, neg_ids, emb, out_b,
                                                 emb_ln_g, emb_ln_b, out_ln_g, out_ln_b,
                                                 (float*)d_out);
}